// Round 3
// baseline (5452.933 us; speedup 1.0000x reference)
//
#include <hip/hip_runtime.h>
#include <hip/hip_bf16.h>
#include <stdint.h>

#define LATENT 256
#define HIDDEN 1024
#define GOUT 512
#define NB 32
#define TT 512
#define G3 1536

typedef float f32x4 __attribute__((ext_vector_type(4)));
typedef short s16x8 __attribute__((ext_vector_type(8)));
typedef uint32_t u32;
typedef unsigned long long u64;

#define GLP(p) ((const __attribute__((address_space(1))) u32*)(p))
#define LLP(p) ((__attribute__((address_space(3))) u32*)(p))

__device__ __forceinline__ short f2bf(float f) {
  u32 u = __builtin_bit_cast(u32, f);
  u32 r = (u + 0x7FFFu + ((u >> 16) & 1u)) >> 16;
  return (short)r;
}
__device__ __forceinline__ float bf2f(short s) {
  u32 u = ((u32)(unsigned short)s) << 16;
  return __builtin_bit_cast(float, u);
}
__device__ __forceinline__ u32 pk2(float a, float b) {
  return (u32)(unsigned short)f2bf(a) | ((u32)(unsigned short)f2bf(b) << 16);
}
__device__ __forceinline__ s16x8 f2bf8(float4 a, float4 b) {
  s16x8 r;
  r[0] = f2bf(a.x); r[1] = f2bf(a.y); r[2] = f2bf(a.z); r[3] = f2bf(a.w);
  r[4] = f2bf(b.x); r[5] = f2bf(b.y); r[6] = f2bf(b.z); r[7] = f2bf(b.w);
  return r;
}
__device__ __forceinline__ float ldgx(const float* p) { return *p; }
__device__ __forceinline__ float ldgx(const short* p) { return bf2f(*p); }
__device__ __forceinline__ u64 ald(const u64* p) {
  return __hip_atomic_load(p, __ATOMIC_RELAXED, __HIP_MEMORY_SCOPE_AGENT);
}

// ---------------- fc + relu ----------------
__global__ __launch_bounds__(256) void fc_kernel(const float* __restrict__ z,
                                                 const float* __restrict__ fc_w,
                                                 const float* __restrict__ fc_b,
                                                 float* __restrict__ hfc) {
  __shared__ float zs[LATENT];
  int tid = threadIdx.x;
  int gid = blockIdx.x * 256 + tid;
  int b = gid >> 10, j = gid & 1023;
  zs[tid] = z[b * LATENT + tid];
  __syncthreads();
  const float4* wr = (const float4*)(fc_w + (size_t)j * LATENT);
  float s = 0.f;
#pragma unroll
  for (int k = 0; k < LATENT / 4; ++k) {
    float4 wv = wr[k];
    float4 zv = *(const float4*)&zs[k * 4];
    s += wv.x * zv.x + wv.y * zv.y + wv.z * zv.z + wv.w * zv.w;
  }
  s += fc_b[j];
  hfc[gid] = fmaxf(s, 0.f);
}

// ------------- x0[t][b][k] = bf16(hfc[b][k] + chord[b][t][k]/100) -------------
__global__ __launch_bounds__(256) void x0_kernel(const float* __restrict__ hfc,
                                                 const float* __restrict__ chord,
                                                 short* __restrict__ x0) {
  int r = blockIdx.x;          // r = t*32 + b
  int b = r & 31, t = r >> 5;
  int k = threadIdx.x * 4;
  float4 c = *(const float4*)(chord + ((size_t)b * TT + t) * HIDDEN + k);
  float4 h = *(const float4*)(hfc + (size_t)b * HIDDEN + k);
  u32 p0 = pk2(h.x + c.x * 0.01f, h.y + c.y * 0.01f);
  u32 p1 = pk2(h.z + c.z * 0.01f, h.w + c.w * 0.01f);
  uint2 pv; pv.x = p0; pv.y = p1;
  *(uint2*)(x0 + (size_t)r * HIDDEN + k) = pv;
}

// ---------------- fp32 -> bf16 weight convert ----------------
__global__ __launch_bounds__(256) void cvt_kernel(const float* __restrict__ src,
                                                  short* __restrict__ dst, int n4) {
  int i = blockIdx.x * 256 + threadIdx.x;
  if (i < n4) {
    float4 v = ((const float4*)src)[i];
    uint2 pv; pv.x = pk2(v.x, v.y); pv.y = pk2(v.z, v.w);
    ((uint2*)dst)[i] = pv;
  }
}

// ---------------- GEMM: C[M][N] = A[M][K](bf16) @ Bw[N][K]^T(bf16) ----------------
template <typename OutT>
__global__ __launch_bounds__(256) void gemm_bt(const short* __restrict__ A,
                                               const short* __restrict__ Bw,
                                               OutT* __restrict__ C, int M, int N, int K) {
  __shared__ short As[128 * 32];
  __shared__ short Bs[128 * 32];
  const int tid = threadIdx.x;
  const int lane = tid & 63, wave = tid >> 6;
  const int l15 = lane & 15, quad = lane >> 4;
  const int n0 = blockIdx.x * 128, m0 = blockIdx.y * 128;
  const int wm = (wave >> 1) * 64, wn = (wave & 1) * 64;
  f32x4 acc[4][4] = {};
  for (int k0 = 0; k0 < K; k0 += 32) {
#pragma unroll
    for (int c = 0; c < 2; ++c) {
      int idx = c * 256 + tid;
      int row = idx >> 2, cs = (idx & 3) * 8;
      const u32* ga = (const u32*)(A + (size_t)(m0 + row) * K + k0 + cs);
      const u32* gb = (const u32*)(Bw + (size_t)(n0 + row) * K + k0 + cs);
      u32* sa = (u32*)As + (size_t)(c * 256 + wave * 64) * 4;
      u32* sb = (u32*)Bs + (size_t)(c * 256 + wave * 64) * 4;
      __builtin_amdgcn_global_load_lds(GLP(ga), LLP(sa), 16, 0, 0);
      __builtin_amdgcn_global_load_lds(GLP(gb), LLP(sb), 16, 0, 0);
    }
    __syncthreads();
    s16x8 af[4], bfr[4];
#pragma unroll
    for (int i = 0; i < 4; ++i)
      af[i] = *(const s16x8*)(As + (wm + i * 16 + l15) * 32 + quad * 8);
#pragma unroll
    for (int j = 0; j < 4; ++j)
      bfr[j] = *(const s16x8*)(Bs + (wn + j * 16 + l15) * 32 + quad * 8);
#pragma unroll
    for (int i = 0; i < 4; ++i)
#pragma unroll
      for (int j = 0; j < 4; ++j)
        acc[i][j] = __builtin_amdgcn_mfma_f32_16x16x32_bf16(af[i], bfr[j], acc[i][j], 0, 0, 0);
    __syncthreads();
  }
#pragma unroll
  for (int i = 0; i < 4; ++i)
#pragma unroll
    for (int j = 0; j < 4; ++j)
#pragma unroll
      for (int r = 0; r < 4; ++r) {
        int m = m0 + wm + i * 16 + quad * 4 + r;
        int n = n0 + wn + j * 16 + l15;
        float v = acc[i][j][r];
        if constexpr (__is_same(OutT, float)) C[(size_t)m * N + n] = v;
        else C[(size_t)m * N + n] = f2bf(v);
      }
}

// ================= wave-autonomous GRU layer (v5b) =================
// 2 groups x 16 batches; 32 waves/group, each wave owns 16 units for ALL 16
// batches and is fully self-contained:
//   - w_hh frags for 3 gates x 16 units persistent in 192 VGPRs
//   - A-frags (h(t-1), 16 batches x K=512) polled DIRECTLY from the tagged
//     global ring into registers (depth-4 pipelined, per-wave staggered kb
//     order so waves don't hammer the same words)
//   - MFMA C layout (col=unit=l15, row=batch=quad*4+r) => all 3 gate values
//     for a (batch,unit) land in the SAME lane -> combine fully in-register
//   - tagged h store (tag hi32 = tb+t+1, payload 2 bf16), issued FIRST in the
//     epilogue (before gx prefetch and x/f stores) for earliest visibility
// NO __syncthreads / LDS anywhere in the recurrence loop.
// Ring: depth-2 per group. Safety: a wave enters step t only after observing
// EVERY word of h(t-1) (the wave polls the full slot); producers' reads of
// slot t&1 (h(t-2)) are data-dependent predecessors of their observed h(t-1)
// stores, so overwrite of slot t&1 is causally after all peer reads.
// Tag+payload share one u64 -> single-word atomicity; relaxed suffices.
// Per-layer tag_base prevents stale-tag matches across the 3 launches;
// clr_kernel zeroes tags each launch. Groups pinned XCD-local via bid&7
// in {0,4} (perf heuristic only; agent scope keeps cross-XCD correct).
__global__ __launch_bounds__(256) void clr_kernel(u64* __restrict__ p) {
  p[(size_t)blockIdx.x * 256 + threadIdx.x] = 0ull;
}

template <typename GxT>
__global__ __launch_bounds__(64) void gru_seq(const GxT* __restrict__ gx,      // [T][32][1536]
                                              const float* __restrict__ w_hh,  // [1536][512]
                                              const float* __restrict__ b_ih,
                                              const float* __restrict__ b_hh,
                                              u64* __restrict__ h_buf,         // [2 grp][2 slot][16 b][256 w]
                                              int tb,
                                              short* __restrict__ x_out,       // [T][32][512] bf16 or null
                                              float* __restrict__ f_out,       // [32][T][512] fp32 or null
                                              const int* __restrict__ seq_lens) {
  const int bid = blockIdx.x;
  const int xs = bid & 7;
  int g;
  if (xs == 0) g = 0;
  else if (xs == 4) g = 1;
  else return;                                // dummy WG (XCD-pinning pad)
  const int wq = bid >> 3;                    // 0..31: unit-block
  const int u0 = wq * 16;
  const int lane = threadIdx.x;               // 64 threads = 1 wave
  const int l15 = lane & 15, quad = lane >> 4;
  const int u = u0 + l15;

  u64* hb = h_buf + (size_t)g * 8192;
  const int st = wq & 15;                     // staggered kb start

  // --- persistent w_hh fragments, loaded in staggered kb order ---
  s16x8 wf[48];
#pragma unroll
  for (int i = 0; i < 16; ++i) {
    const int kb = (st + i) & 15;
#pragma unroll
    for (int gt = 0; gt < 3; ++gt) {
      const float* p = w_hh + (size_t)(gt * 512 + u) * 512 + kb * 32 + quad * 8;
      wf[gt * 16 + i] = f2bf8(*(const float4*)p, *(const float4*)(p + 4));
    }
  }

  const float bihr = b_ih[u], bihz = b_ih[512 + u], bihn = b_ih[1024 + u];
  const float bhhr = b_hh[u], bhhz = b_hh[512 + u], bhhn = b_hh[1024 + u];

  float hprev[4] = {0.f, 0.f, 0.f, 0.f};
  int slen[4] = {0, 0, 0, 0};
  float pgx[3][4];
#pragma unroll
  for (int r = 0; r < 4; ++r) {
    const int gb = g * 16 + quad * 4 + r;
    if (f_out) slen[r] = seq_lens[gb];
#pragma unroll
    for (int gt = 0; gt < 3; ++gt)
      pgx[gt][r] = ldgx(&gx[(size_t)gb * G3 + gt * 512 + u]);   // t=0
  }

  for (int t = 0; t < TT; ++t) {
    f32x4 ar = {0.f, 0.f, 0.f, 0.f}, az = ar, an = ar;
    if (t > 0) {
      const u64* sb = hb + ((t - 1) & 1) * 4096 + l15 * 256 + quad * 4;
      const u32 want = (u32)(tb + t);
      u64 pw[4][4];
#pragma unroll
      for (int p = 0; p < 4; ++p) {
        const u64* a = sb + ((st + p) & 15) * 16;
        pw[p][0] = ald(a); pw[p][1] = ald(a + 1); pw[p][2] = ald(a + 2); pw[p][3] = ald(a + 3);
      }
#pragma unroll
      for (int i = 0; i < 16; ++i) {
        const int p = i & 3;
        const u64* a = sb + ((st + i) & 15) * 16;
        u64 v0 = pw[p][0], v1 = pw[p][1], v2 = pw[p][2], v3 = pw[p][3];
        while (((((u32)(v0 >> 32)) ^ want) | (((u32)(v1 >> 32)) ^ want) |
                (((u32)(v2 >> 32)) ^ want) | (((u32)(v3 >> 32)) ^ want)) != 0u) {
          v0 = ald(a); v1 = ald(a + 1); v2 = ald(a + 2); v3 = ald(a + 3);
        }
        uint4 uu; uu.x = (u32)v0; uu.y = (u32)v1; uu.z = (u32)v2; uu.w = (u32)v3;
        const s16x8 fr = __builtin_bit_cast(s16x8, uu);
        ar = __builtin_amdgcn_mfma_f32_16x16x32_bf16(fr, wf[i],      ar, 0, 0, 0);
        az = __builtin_amdgcn_mfma_f32_16x16x32_bf16(fr, wf[16 + i], az, 0, 0, 0);
        an = __builtin_amdgcn_mfma_f32_16x16x32_bf16(fr, wf[32 + i], an, 0, 0, 0);
        if (i < 12) {
          const u64* a2 = sb + ((st + i + 4) & 15) * 16;
          pw[p][0] = ald(a2); pw[p][1] = ald(a2 + 1); pw[p][2] = ald(a2 + 2); pw[p][3] = ald(a2 + 3);
        }
      }
    }

    // ---- in-register combine (reads pgx of step t directly) ----
    float hs[4];
#pragma unroll
    for (int r = 0; r < 4; ++r) {
      const float xr = pgx[0][r] + bihr + ar[r] + bhhr;
      const float xz = pgx[1][r] + bihz + az[r] + bhhz;
      const float rr = 1.f / (1.f + __expf(-xr));
      const float zz = 1.f / (1.f + __expf(-xz));
      const float pre = pgx[2][r] + bihn + rr * (an[r] + bhhn);
      const float ax = fabsf(pre);
      const float e = __expf(-2.f * ax);
      const float nn = copysignf((1.f - e) / (1.f + e), pre);
      const float h = (1.f - zz) * nn + zz * hprev[r];
      hprev[r] = h; hs[r] = h;
    }
    // ---- tagged h stores FIRST: earliest visibility to consumers ----
    u64* dst = hb + (t & 1) * 4096;
    const u64 tg = ((u64)(u32)(tb + t + 1)) << 32;
#pragma unroll
    for (int r = 0; r < 4; ++r) {
      const float other = __shfl_xor(hs[r], 1);
      if (!(lane & 1))
        __hip_atomic_store(dst + (quad * 4 + r) * 256 + (u >> 1), (u64)pk2(hs[r], other) | tg,
                           __ATOMIC_RELAXED, __HIP_MEMORY_SCOPE_AGENT);
    }
    // ---- gx prefetch for t+1 (issue-only; consumed next step) ----
    if (t + 1 < TT) {
#pragma unroll
      for (int gt = 0; gt < 3; ++gt)
#pragma unroll
        for (int r = 0; r < 4; ++r) {
          const int gb = g * 16 + quad * 4 + r;
          pgx[gt][r] = ldgx(&gx[(size_t)((t + 1) * NB + gb) * G3 + gt * 512 + u]);
        }
    }
    // ---- output stores (off the critical path) ----
#pragma unroll
    for (int r = 0; r < 4; ++r) {
      const int gb = g * 16 + quad * 4 + r;
      if (x_out) x_out[(size_t)(t * NB + gb) * 512 + u] = f2bf(hs[r]);
      if (f_out) f_out[((size_t)gb * TT + t) * 512 + u] = (t < slen[r]) ? hs[r] : 0.f;
    }
  }
}

extern "C" void kernel_launch(void* const* d_in, const int* in_sizes, int n_in,
                              void* d_out, int out_size, void* d_ws, size_t ws_size,
                              hipStream_t stream) {
  (void)in_sizes; (void)n_in; (void)out_size;
  const float* z       = (const float*)d_in[0];
  const int*   seq     = (const int*)d_in[1];
  const float* chord   = (const float*)d_in[2];
  const float* fc_w    = (const float*)d_in[3];
  const float* fc_b    = (const float*)d_in[4];
  const float* w_ih[3] = {(const float*)d_in[5], (const float*)d_in[9],  (const float*)d_in[13]};
  const float* w_hh[3] = {(const float*)d_in[6], (const float*)d_in[10], (const float*)d_in[14]};
  const float* b_ih[3] = {(const float*)d_in[7], (const float*)d_in[11], (const float*)d_in[15]};
  const float* b_hh[3] = {(const float*)d_in[8], (const float*)d_in[12], (const float*)d_in[16]};

  char* w = (char*)d_ws;
  size_t off = 0;
  auto alloc = [&](size_t bytes) -> void* {
    void* p = w + off;
    off = (off + bytes + 255) & ~(size_t)255;
    return p;
  };
  u64*   hbuf = (u64*)alloc((size_t)2 * 8192 * 8);           // tagged h rings (128 KB)
  float* hfc  = (float*)alloc((size_t)NB * HIDDEN * 4);
  short* x0   = (short*)alloc((size_t)TT * NB * HIDDEN * 2);
  short* x1   = (short*)alloc((size_t)TT * NB * GOUT * 2);   // reused as x2
  short* w0b  = (short*)alloc((size_t)G3 * HIDDEN * 2);
  short* w1b  = (short*)alloc((size_t)G3 * GOUT * 2);
  short* w2b  = (short*)alloc((size_t)G3 * GOUT * 2);
  size_t fixed = off;
  bool gx_f32 = (fixed + (size_t)TT * NB * G3 * 4) <= ws_size;
  void* gx = alloc(gx_f32 ? (size_t)TT * NB * G3 * 4 : (size_t)TT * NB * G3 * 2);

  clr_kernel<<<64, 256, 0, stream>>>(hbuf);
  fc_kernel<<<128, 256, 0, stream>>>(z, fc_w, fc_b, hfc);
  x0_kernel<<<TT * NB, 256, 0, stream>>>(hfc, chord, x0);
  cvt_kernel<<<(G3 * HIDDEN / 4 + 255) / 256, 256, 0, stream>>>(w_ih[0], w0b, G3 * HIDDEN / 4);
  cvt_kernel<<<(G3 * GOUT / 4 + 255) / 256, 256, 0, stream>>>(w_ih[1], w1b, G3 * GOUT / 4);
  cvt_kernel<<<(G3 * GOUT / 4 + 255) / 256, 256, 0, stream>>>(w_ih[2], w2b, G3 * GOUT / 4);

  dim3 gg(G3 / 128, TT * NB / 128);
  if (gx_f32) {
    float* gxf = (float*)gx;
    gemm_bt<float><<<gg, 256, 0, stream>>>(x0, w0b, gxf, TT * NB, G3, HIDDEN);
    gru_seq<float><<<256, 64, 0, stream>>>(gxf, w_hh[0], b_ih[0], b_hh[0], hbuf, 0 * 1024, x1, nullptr, seq);
    gemm_bt<float><<<gg, 256, 0, stream>>>(x1, w1b, gxf, TT * NB, G3, GOUT);
    gru_seq<float><<<256, 64, 0, stream>>>(gxf, w_hh[1], b_ih[1], b_hh[1], hbuf, 1 * 1024, x1, nullptr, seq);
    gemm_bt<float><<<gg, 256, 0, stream>>>(x1, w2b, gxf, TT * NB, G3, GOUT);
    gru_seq<float><<<256, 64, 0, stream>>>(gxf, w_hh[2], b_ih[2], b_hh[2], hbuf, 2 * 1024, nullptr, (float*)d_out, seq);
  } else {
    short* gxb = (short*)gx;
    gemm_bt<short><<<gg, 256, 0, stream>>>(x0, w0b, gxb, TT * NB, G3, HIDDEN);
    gru_seq<short><<<256, 64, 0, stream>>>(gxb, w_hh[0], b_ih[0], b_hh[0], hbuf, 0 * 1024, x1, nullptr, seq);
    gemm_bt<short><<<gg, 256, 0, stream>>>(x1, w1b, gxb, TT * NB, G3, GOUT);
    gru_seq<short><<<256, 64, 0, stream>>>(gxb, w_hh[1], b_ih[1], b_hh[1], hbuf, 1 * 1024, x1, nullptr, seq);
    gemm_bt<short><<<gg, 256, 0, stream>>>(x1, w2b, gxb, TT * NB, G3, GOUT);
    gru_seq<short><<<256, 64, 0, stream>>>(gxb, w_hh[2], b_ih[2], b_hh[2], hbuf, 2 * 1024, nullptr, (float*)d_out, seq);
  }
}

// Round 4
// 5002.289 us; speedup vs baseline: 1.0901x; 1.0901x over previous
//
#include <hip/hip_runtime.h>
#include <hip/hip_bf16.h>
#include <stdint.h>

#define LATENT 256
#define HIDDEN 1024
#define GOUT 512
#define NB 32
#define TT 512
#define G3 1536

typedef float f32x4 __attribute__((ext_vector_type(4)));
typedef short s16x8 __attribute__((ext_vector_type(8)));
typedef uint32_t u32;
typedef unsigned long long u64;

#define GLP(p) ((const __attribute__((address_space(1))) u32*)(p))
#define LLP(p) ((__attribute__((address_space(3))) u32*)(p))

__device__ __forceinline__ short f2bf(float f) {
  u32 u = __builtin_bit_cast(u32, f);
  u32 r = (u + 0x7FFFu + ((u >> 16) & 1u)) >> 16;
  return (short)r;
}
__device__ __forceinline__ float bf2f(short s) {
  u32 u = ((u32)(unsigned short)s) << 16;
  return __builtin_bit_cast(float, u);
}
__device__ __forceinline__ u32 pk2(float a, float b) {
  return (u32)(unsigned short)f2bf(a) | ((u32)(unsigned short)f2bf(b) << 16);
}
__device__ __forceinline__ s16x8 f2bf8(float4 a, float4 b) {
  s16x8 r;
  r[0] = f2bf(a.x); r[1] = f2bf(a.y); r[2] = f2bf(a.z); r[3] = f2bf(a.w);
  r[4] = f2bf(b.x); r[5] = f2bf(b.y); r[6] = f2bf(b.z); r[7] = f2bf(b.w);
  return r;
}
__device__ __forceinline__ float ldgx(const float* p) { return *p; }
__device__ __forceinline__ float ldgx(const short* p) { return bf2f(*p); }
__device__ __forceinline__ u64 ald(const u64* p) {
  return __hip_atomic_load(p, __ATOMIC_RELAXED, __HIP_MEMORY_SCOPE_AGENT);
}

// ---------------- fc + relu ----------------
__global__ __launch_bounds__(256) void fc_kernel(const float* __restrict__ z,
                                                 const float* __restrict__ fc_w,
                                                 const float* __restrict__ fc_b,
                                                 float* __restrict__ hfc) {
  __shared__ float zs[LATENT];
  int tid = threadIdx.x;
  int gid = blockIdx.x * 256 + tid;
  int b = gid >> 10, j = gid & 1023;
  zs[tid] = z[b * LATENT + tid];
  __syncthreads();
  const float4* wr = (const float4*)(fc_w + (size_t)j * LATENT);
  float s = 0.f;
#pragma unroll
  for (int k = 0; k < LATENT / 4; ++k) {
    float4 wv = wr[k];
    float4 zv = *(const float4*)&zs[k * 4];
    s += wv.x * zv.x + wv.y * zv.y + wv.z * zv.z + wv.w * zv.w;
  }
  s += fc_b[j];
  hfc[gid] = fmaxf(s, 0.f);
}

// ------------- x0[t][b][k] = bf16(hfc[b][k] + chord[b][t][k]/100) -------------
__global__ __launch_bounds__(256) void x0_kernel(const float* __restrict__ hfc,
                                                 const float* __restrict__ chord,
                                                 short* __restrict__ x0) {
  int r = blockIdx.x;          // r = t*32 + b
  int b = r & 31, t = r >> 5;
  int k = threadIdx.x * 4;
  float4 c = *(const float4*)(chord + ((size_t)b * TT + t) * HIDDEN + k);
  float4 h = *(const float4*)(hfc + (size_t)b * HIDDEN + k);
  u32 p0 = pk2(h.x + c.x * 0.01f, h.y + c.y * 0.01f);
  u32 p1 = pk2(h.z + c.z * 0.01f, h.w + c.w * 0.01f);
  uint2 pv; pv.x = p0; pv.y = p1;
  *(uint2*)(x0 + (size_t)r * HIDDEN + k) = pv;
}

// ---------------- fp32 -> bf16 weight convert ----------------
__global__ __launch_bounds__(256) void cvt_kernel(const float* __restrict__ src,
                                                  short* __restrict__ dst, int n4) {
  int i = blockIdx.x * 256 + threadIdx.x;
  if (i < n4) {
    float4 v = ((const float4*)src)[i];
    uint2 pv; pv.x = pk2(v.x, v.y); pv.y = pk2(v.z, v.w);
    ((uint2*)dst)[i] = pv;
  }
}

// ---------------- GEMM: C[M][N] = A[M][K](bf16) @ Bw[N][K]^T(bf16) ----------------
template <typename OutT>
__global__ __launch_bounds__(256) void gemm_bt(const short* __restrict__ A,
                                               const short* __restrict__ Bw,
                                               OutT* __restrict__ C, int M, int N, int K) {
  __shared__ short As[128 * 32];
  __shared__ short Bs[128 * 32];
  const int tid = threadIdx.x;
  const int lane = tid & 63, wave = tid >> 6;
  const int l15 = lane & 15, quad = lane >> 4;
  const int n0 = blockIdx.x * 128, m0 = blockIdx.y * 128;
  const int wm = (wave >> 1) * 64, wn = (wave & 1) * 64;
  f32x4 acc[4][4] = {};
  for (int k0 = 0; k0 < K; k0 += 32) {
#pragma unroll
    for (int c = 0; c < 2; ++c) {
      int idx = c * 256 + tid;
      int row = idx >> 2, cs = (idx & 3) * 8;
      const u32* ga = (const u32*)(A + (size_t)(m0 + row) * K + k0 + cs);
      const u32* gb = (const u32*)(Bw + (size_t)(n0 + row) * K + k0 + cs);
      u32* sa = (u32*)As + (size_t)(c * 256 + wave * 64) * 4;
      u32* sb = (u32*)Bs + (size_t)(c * 256 + wave * 64) * 4;
      __builtin_amdgcn_global_load_lds(GLP(ga), LLP(sa), 16, 0, 0);
      __builtin_amdgcn_global_load_lds(GLP(gb), LLP(sb), 16, 0, 0);
    }
    __syncthreads();
    s16x8 af[4], bfr[4];
#pragma unroll
    for (int i = 0; i < 4; ++i)
      af[i] = *(const s16x8*)(As + (wm + i * 16 + l15) * 32 + quad * 8);
#pragma unroll
    for (int j = 0; j < 4; ++j)
      bfr[j] = *(const s16x8*)(Bs + (wn + j * 16 + l15) * 32 + quad * 8);
#pragma unroll
    for (int i = 0; i < 4; ++i)
#pragma unroll
      for (int j = 0; j < 4; ++j)
        acc[i][j] = __builtin_amdgcn_mfma_f32_16x16x32_bf16(af[i], bfr[j], acc[i][j], 0, 0, 0);
    __syncthreads();
  }
#pragma unroll
  for (int i = 0; i < 4; ++i)
#pragma unroll
    for (int j = 0; j < 4; ++j)
#pragma unroll
      for (int r = 0; r < 4; ++r) {
        int m = m0 + wm + i * 16 + quad * 4 + r;
        int n = n0 + wn + j * 16 + l15;
        float v = acc[i][j][r];
        if constexpr (__is_same(OutT, float)) C[(size_t)m * N + n] = v;
        else C[(size_t)m * N + n] = f2bf(v);
      }
}

// ================= GRU layer v6: coalesced poll + LDS stage + in-reg combine ==
// Post-mortem v5b: per-wave strided polls = 64 uncoalesced 8B line-requests per
// instruction -> ~131K L2 line-req/XCD/step -> 8200 cy/step. Fix: poll THREAD-
// LINEAR (word j*256+tid: lanes contiguous, fully coalesced, 512 line-req/WG),
// stage payload once per WG into LDS, read A-frags from LDS (b128, swizzled).
//
// Shape: 2 groups x 16 batches; 8 WGs/group x 256 thr (4 waves, 1/SIMD).
// Wave v of WG wg owns units wg*64 + v*16 + l15 for ALL 16 batches:
//   - w_hh frags 3 gates x 16 kb persistent (192 VGPR)
//   - MFMA C layout (col=unit=l15, row=batch=quad*4+r) -> all 3 gates for a
//     (batch,unit) in the SAME lane -> combine fully in-register (no lds_c
//     handoff, no dedicated combine waves)
//   - tagged h store (tag hi32 = tb+t+1, payload 2 bf16), coalesced
// ONE barrier per step; LDS h tile double-buffered [t&1] so staging t+2 can
// never race readers of step t (both fenced by barrier t+1).
// LDS swizzle addr(r,c) = r*256 + (c ^ ((r&7)<<2) ^ ((r&1)<<4)): read banks
// per quad spread over all 8 4-bank groups, exactly 2 rows/group = free
// (m136); stage writes are row-uniform stride-1 = conflict-free.
// Ring: depth-2/group, v5b-proven protocol (tag+payload in one u64, relaxed
// agent atomics; a WG enters step t only after observing EVERY word of h(t-1),
// whose values are data-dependent on their producers' reads of slot t&1 ->
// overwrite is causally safe). Per-layer tag_base; clr_kernel zeroes tags.
// Groups pinned XCD-local via bid&7 in {0,4} (perf heuristic only).
__global__ __launch_bounds__(256) void clr_kernel(u64* __restrict__ p) {
  p[(size_t)blockIdx.x * 256 + threadIdx.x] = 0ull;
}

template <typename GxT>
__global__ __launch_bounds__(256, 1) void gru_seq(const GxT* __restrict__ gx,      // [T][32][1536]
                                                  const float* __restrict__ w_hh,  // [1536][512]
                                                  const float* __restrict__ b_ih,
                                                  const float* __restrict__ b_hh,
                                                  u64* __restrict__ h_buf,         // [2 grp][2 slot][16 b][256 w]
                                                  int tb,
                                                  short* __restrict__ x_out,       // [T][32][512] bf16 or null
                                                  float* __restrict__ f_out,       // [32][T][512] fp32 or null
                                                  const int* __restrict__ seq_lens) {
  const int bid = blockIdx.x;                 // grid 64
  const int xs = bid & 7;
  int g;
  if (xs == 0) g = 0;
  else if (xs == 4) g = 1;
  else return;                                // dummy WG (XCD-pinning pad)
  const int wg = bid >> 3;                    // 0..7: unit-block of 64
  const int tid = threadIdx.x;                // 0..255
  const int lane = tid & 63, wave = tid >> 6; // 4 waves
  const int l15 = lane & 15, quad = lane >> 4;
  const int u = wg * 64 + wave * 16 + l15;    // owned unit

  __shared__ u32 h_lds[2][16 * 256];          // 32 KB double-buffered h tile

  u64* hb = h_buf + (size_t)g * 8192;

  // --- persistent w_hh fragments: 3 gates x 16 kb ---
  s16x8 wf[48];
#pragma unroll
  for (int kb = 0; kb < 16; ++kb)
#pragma unroll
    for (int gt = 0; gt < 3; ++gt) {
      const float* p = w_hh + (size_t)(gt * 512 + u) * 512 + kb * 32 + quad * 8;
      wf[gt * 16 + kb] = f2bf8(*(const float4*)p, *(const float4*)(p + 4));
    }

  const float bihr = b_ih[u], bihz = b_ih[512 + u], bihn = b_ih[1024 + u];
  const float bhhr = b_hh[u], bhhz = b_hh[512 + u], bhhn = b_hh[1024 + u];

  float hprev[4] = {0.f, 0.f, 0.f, 0.f};
  int slen[4] = {0, 0, 0, 0};
  float pgx[3][4];
#pragma unroll
  for (int r = 0; r < 4; ++r) {
    const int gb = g * 16 + quad * 4 + r;
    if (f_out) slen[r] = seq_lens[gb];
#pragma unroll
    for (int gt = 0; gt < 3; ++gt)
      pgx[gt][r] = ldgx(&gx[(size_t)gb * G3 + gt * 512 + u]);   // t=0
  }

  for (int t = 0; t < TT; ++t) {
    // ---- coalesced poll of h(t-1) + LDS stage (thread-linear mapping) ----
    if (t > 0) {
      const u64* src = hb + ((t - 1) & 1) * 4096;
      const u32 want = (u32)(tb + t);
      u32* dl = h_lds[t & 1];
      u64 v[16];
#pragma unroll
      for (int j = 0; j < 16; ++j) v[j] = ald(src + j * 256 + tid);
#pragma unroll
      for (int j = 0; j < 16; ++j) {
        while ((u32)(v[j] >> 32) != want) v[j] = ald(src + j * 256 + tid);
        dl[j * 256 + (tid ^ ((j & 7) << 2) ^ ((j & 1) << 4))] = (u32)v[j];
      }
    }
    __syncthreads();

    // ---- gate MFMAs from LDS (3 round-robin acc chains, dep distance 3) ----
    f32x4 ar = {0.f, 0.f, 0.f, 0.f}, az = ar, an = ar;
    if (t > 0) {
      const u32* hl = h_lds[t & 1];
      const int rbase = l15 * 256;
      const int rx = ((l15 & 7) << 2) ^ ((l15 & 1) << 4);
#pragma unroll
      for (int i = 0; i < 16; ++i) {
        const s16x8 fr = *(const s16x8*)&hl[rbase + ((quad * 4 + i * 16) ^ rx)];
        ar = __builtin_amdgcn_mfma_f32_16x16x32_bf16(fr, wf[i],      ar, 0, 0, 0);
        az = __builtin_amdgcn_mfma_f32_16x16x32_bf16(fr, wf[16 + i], az, 0, 0, 0);
        an = __builtin_amdgcn_mfma_f32_16x16x32_bf16(fr, wf[32 + i], an, 0, 0, 0);
      }
    }

    // ---- in-register combine ----
    float hs[4];
#pragma unroll
    for (int r = 0; r < 4; ++r) {
      const float xr = pgx[0][r] + bihr + ar[r] + bhhr;
      const float xz = pgx[1][r] + bihz + az[r] + bhhz;
      const float rr = 1.f / (1.f + __expf(-xr));
      const float zz = 1.f / (1.f + __expf(-xz));
      const float pre = pgx[2][r] + bihn + rr * (an[r] + bhhn);
      const float ax = fabsf(pre);
      const float e = __expf(-2.f * ax);
      const float nn = copysignf((1.f - e) / (1.f + e), pre);
      const float h = (1.f - zz) * nn + zz * hprev[r];
      hprev[r] = h; hs[r] = h;
    }
    // ---- tagged h stores first (earliest visibility; coalesced) ----
    u64* dst = hb + (t & 1) * 4096;
    const u64 tg = ((u64)(u32)(tb + t + 1)) << 32;
#pragma unroll
    for (int r = 0; r < 4; ++r) {
      const float other = __shfl_xor(hs[r], 1);
      if (!(lane & 1))
        __hip_atomic_store(dst + (quad * 4 + r) * 256 + (u >> 1), (u64)pk2(hs[r], other) | tg,
                           __ATOMIC_RELAXED, __HIP_MEMORY_SCOPE_AGENT);
    }
    // ---- gx prefetch for t+1 (latency hidden under next poll) ----
    if (t + 1 < TT) {
#pragma unroll
      for (int gt = 0; gt < 3; ++gt)
#pragma unroll
        for (int r = 0; r < 4; ++r) {
          const int gb = g * 16 + quad * 4 + r;
          pgx[gt][r] = ldgx(&gx[(size_t)((t + 1) * NB + gb) * G3 + gt * 512 + u]);
        }
    }
    // ---- output stores (off the critical path) ----
#pragma unroll
    for (int r = 0; r < 4; ++r) {
      const int gb = g * 16 + quad * 4 + r;
      if (x_out) x_out[(size_t)(t * NB + gb) * 512 + u] = f2bf(hs[r]);
      if (f_out) f_out[((size_t)gb * TT + t) * 512 + u] = (t < slen[r]) ? hs[r] : 0.f;
    }
  }
}

extern "C" void kernel_launch(void* const* d_in, const int* in_sizes, int n_in,
                              void* d_out, int out_size, void* d_ws, size_t ws_size,
                              hipStream_t stream) {
  (void)in_sizes; (void)n_in; (void)out_size;
  const float* z       = (const float*)d_in[0];
  const int*   seq     = (const int*)d_in[1];
  const float* chord   = (const float*)d_in[2];
  const float* fc_w    = (const float*)d_in[3];
  const float* fc_b    = (const float*)d_in[4];
  const float* w_ih[3] = {(const float*)d_in[5], (const float*)d_in[9],  (const float*)d_in[13]};
  const float* w_hh[3] = {(const float*)d_in[6], (const float*)d_in[10], (const float*)d_in[14]};
  const float* b_ih[3] = {(const float*)d_in[7], (const float*)d_in[11], (const float*)d_in[15]};
  const float* b_hh[3] = {(const float*)d_in[8], (const float*)d_in[12], (const float*)d_in[16]};

  char* w = (char*)d_ws;
  size_t off = 0;
  auto alloc = [&](size_t bytes) -> void* {
    void* p = w + off;
    off = (off + bytes + 255) & ~(size_t)255;
    return p;
  };
  u64*   hbuf = (u64*)alloc((size_t)2 * 8192 * 8);           // tagged h rings (128 KB)
  float* hfc  = (float*)alloc((size_t)NB * HIDDEN * 4);
  short* x0   = (short*)alloc((size_t)TT * NB * HIDDEN * 2);
  short* x1   = (short*)alloc((size_t)TT * NB * GOUT * 2);   // reused as x2
  short* w0b  = (short*)alloc((size_t)G3 * HIDDEN * 2);
  short* w1b  = (short*)alloc((size_t)G3 * GOUT * 2);
  short* w2b  = (short*)alloc((size_t)G3 * GOUT * 2);
  size_t fixed = off;
  bool gx_f32 = (fixed + (size_t)TT * NB * G3 * 4) <= ws_size;
  void* gx = alloc(gx_f32 ? (size_t)TT * NB * G3 * 4 : (size_t)TT * NB * G3 * 2);

  clr_kernel<<<64, 256, 0, stream>>>(hbuf);
  fc_kernel<<<128, 256, 0, stream>>>(z, fc_w, fc_b, hfc);
  x0_kernel<<<TT * NB, 256, 0, stream>>>(hfc, chord, x0);
  cvt_kernel<<<(G3 * HIDDEN / 4 + 255) / 256, 256, 0, stream>>>(w_ih[0], w0b, G3 * HIDDEN / 4);
  cvt_kernel<<<(G3 * GOUT / 4 + 255) / 256, 256, 0, stream>>>(w_ih[1], w1b, G3 * GOUT / 4);
  cvt_kernel<<<(G3 * GOUT / 4 + 255) / 256, 256, 0, stream>>>(w_ih[2], w2b, G3 * GOUT / 4);

  dim3 gg(G3 / 128, TT * NB / 128);
  if (gx_f32) {
    float* gxf = (float*)gx;
    gemm_bt<float><<<gg, 256, 0, stream>>>(x0, w0b, gxf, TT * NB, G3, HIDDEN);
    gru_seq<float><<<64, 256, 0, stream>>>(gxf, w_hh[0], b_ih[0], b_hh[0], hbuf, 0 * 1024, x1, nullptr, seq);
    gemm_bt<float><<<gg, 256, 0, stream>>>(x1, w1b, gxf, TT * NB, G3, GOUT);
    gru_seq<float><<<64, 256, 0, stream>>>(gxf, w_hh[1], b_ih[1], b_hh[1], hbuf, 1 * 1024, x1, nullptr, seq);
    gemm_bt<float><<<gg, 256, 0, stream>>>(x1, w2b, gxf, TT * NB, G3, GOUT);
    gru_seq<float><<<64, 256, 0, stream>>>(gxf, w_hh[2], b_ih[2], b_hh[2], hbuf, 2 * 1024, nullptr, (float*)d_out, seq);
  } else {
    short* gxb = (short*)gx;
    gemm_bt<short><<<gg, 256, 0, stream>>>(x0, w0b, gxb, TT * NB, G3, HIDDEN);
    gru_seq<short><<<64, 256, 0, stream>>>(gxb, w_hh[0], b_ih[0], b_hh[0], hbuf, 0 * 1024, x1, nullptr, seq);
    gemm_bt<short><<<gg, 256, 0, stream>>>(x1, w1b, gxb, TT * NB, G3, GOUT);
    gru_seq<short><<<64, 256, 0, stream>>>(gxb, w_hh[1], b_ih[1], b_hh[1], hbuf, 1 * 1024, x1, nullptr, seq);
    gemm_bt<short><<<gg, 256, 0, stream>>>(x1, w2b, gxb, TT * NB, G3, GOUT);
    gru_seq<short><<<64, 256, 0, stream>>>(gxb, w_hh[2], b_ih[2], b_hh[2], hbuf, 2 * 1024, nullptr, (float*)d_out, seq);
  }
}